// Round 1
// baseline (87.015 us; speedup 1.0000x reference)
//
#include <hip/hip_runtime.h>

// Maj3: out[n,a] = 3 * sum_G clip( sum_U p[n][U*192+G] * w[a][U*192+G], -1, 1 )
//   n = (b,w,h) over 8x32x32, a = 64 output channels, G = 192, U = 3.
//   p = flattened 3x3 patch of x (layout c*9 + u*3 + v), padded with -1.
//   w in {-1,+1}  ->  x*w == x XOR signbit(w). Weights live as 18 sign-bit
//   dwords per channel in VGPRs (lane = channel a): zero weight traffic in
//   the inner loop.

#define J_   576
#define G_   192
#define NBH  16    // h-positions per block
#define NPW  4     // positions per wave

typedef float f4 __attribute__((ext_vector_type(4)));
typedef unsigned int u32;

// ---- prep: pack sign bits of w[64][576] into bits[d][a], d=0..17 ----------
// bit k of bits[d][a]  <->  sign(w[a][d*32+k])  (1 == negative)
__global__ __launch_bounds__(64) void pack_kernel(const float* __restrict__ w,
                                                  u32* __restrict__ bits) {
    const int a    = blockIdx.x;   // 0..63
    const int lane = threadIdx.x;  // 0..63
    float v[9];
#pragma unroll
    for (int jb = 0; jb < 9; ++jb) v[jb] = w[a * J_ + jb * 64 + lane];
#pragma unroll
    for (int jb = 0; jb < 9; ++jb) {
        unsigned long long m = __ballot(v[jb] < 0.0f);
        if (lane == 0) {
            bits[(2 * jb + 0) * 64 + a] = (u32)m;
            bits[(2 * jb + 1) * 64 + a] = (u32)(m >> 32);
        }
    }
}

// ---- main -----------------------------------------------------------------
// grid 512: block = one (b,w) row half (16 h-positions). 256 thr = 4 waves.
// lane = output channel a; wave wv handles positions ni = wv*4 .. wv*4+3.
template <bool SELF_PACK>
__global__ __launch_bounds__(256) void maj3_kernel(const float* __restrict__ x,
                                                   const float* __restrict__ w,
                                                   const u32* __restrict__ bits,
                                                   float* __restrict__ out) {
    __shared__ u32 bl[18][64];
    __shared__ __align__(16) float p[NBH][J_];  // 36864 B

    const int tid  = threadIdx.x;
    const int lane = tid & 63;
    const int wv   = tid >> 6;
    const int blk  = blockIdx.x;
    const int bw   = blk >> 1;             // b*32 + w
    const int h0   = (blk & 1) * NBH;
    const int b    = bw >> 5;
    const int ww0  = bw & 31;

    if (SELF_PACK) {
        // 64 a x 9 jblk ballots, split across 4 waves (fallback path only)
#pragma unroll 1
        for (int i = 0; i < 16; ++i) {
            const int a = wv * 16 + i;
            float vv[9];
#pragma unroll
            for (int jb = 0; jb < 9; ++jb) vv[jb] = w[a * J_ + jb * 64 + lane];
#pragma unroll
            for (int jb = 0; jb < 9; ++jb) {
                unsigned long long m = __ballot(vv[jb] < 0.0f);
                if (lane == 0) {
                    bl[2 * jb + 0][a] = (u32)m;
                    bl[2 * jb + 1][a] = (u32)(m >> 32);
                }
            }
        }
    }

    // stage x patches: p[ni][c*9 + u*3 + v], -1 outside the image.
    // 16 ni x 9 (u,v) = 144 tasks / 4 waves = 36 per wave; lane = c.
    // LDS word stride 9 (odd) -> 2-way bank aliasing only (free).
#pragma unroll
    for (int i = 0; i < 36; ++i) {
        const int t  = wv * 36 + i;
        const int ni = t / 9, uv = t % 9;
        const int u  = uv / 3, v = uv % 3;
        const int wx = ww0 + u - 1;
        const int hx = h0 + ni + v - 1;
        float val = -1.0f;
        if ((unsigned)wx < 32u && (unsigned)hx < 32u)
            val = x[((b * 32 + wx) * 32 + hx) * 64 + lane];
        p[ni][lane * 9 + uv] = val;
    }
    __syncthreads();

    u32 bb[18];
#pragma unroll
    for (int d = 0; d < 18; ++d)
        bb[d] = SELF_PACK ? bl[d][lane] : bits[d * 64 + lane];

    float acc[NPW] = {0.f, 0.f, 0.f, 0.f};
    const float* pw = &p[wv * NPW][0];

#pragma unroll 1
    for (int d = 0; d < 6; ++d) {
        u32 A = bb[d], Bq = bb[d + 6], Cq = bb[d + 12];
#pragma unroll 2
        for (int k4 = 0; k4 < 8; ++k4) {
            const int g0 = d * 32 + k4 * 4;
            f4 x1[NPW], x2[NPW], x3[NPW];
#pragma unroll
            for (int i = 0; i < NPW; ++i) {
                const float* pr = pw + i * J_;
                x1[i] = *(const f4*)(pr + g0);          // j = G       (broadcast)
                x2[i] = *(const f4*)(pr + g0 + 192);    // j = G + 192
                x3[i] = *(const f4*)(pr + g0 + 384);    // j = G + 384
            }
#pragma unroll
            for (int kk = 0; kk < 4; ++kk) {
                // current LSB of A/Bq/Cq = sign bit for group G = g0+kk
                const u32 m1 = A << 31, m2 = Bq << 31, m3 = Cq << 31;
                A >>= 1; Bq >>= 1; Cq >>= 1;
#pragma unroll
                for (int i = 0; i < NPW; ++i) {
                    float s = __uint_as_float(__float_as_uint(x1[i][kk]) ^ m1)
                            + __uint_as_float(__float_as_uint(x2[i][kk]) ^ m2)
                            + __uint_as_float(__float_as_uint(x3[i][kk]) ^ m3);
                    acc[i] += __builtin_amdgcn_fmed3f(s, -1.0f, 1.0f);
                }
            }
        }
    }

#pragma unroll
    for (int i = 0; i < NPW; ++i) {
        const int h = h0 + wv * NPW + i;
        out[(bw * 32 + h) * 64 + lane] = 3.0f * acc[i];
    }
}

extern "C" void kernel_launch(void* const* d_in, const int* in_sizes, int n_in,
                              void* d_out, int out_size, void* d_ws, size_t ws_size,
                              hipStream_t stream) {
    const float* x = (const float*)d_in[0];   // (8,32,32,64) f32
    const float* w = (const float*)d_in[1];   // (64,576) f32, values +/-1
    float* out = (float*)d_out;               // (8,32,32,64) f32

    if (d_ws && ws_size >= 18 * 64 * sizeof(u32)) {
        u32* bits = (u32*)d_ws;
        pack_kernel<<<64, 64, 0, stream>>>(w, bits);
        maj3_kernel<false><<<512, 256, 0, stream>>>(x, w, bits, out);
    } else {
        maj3_kernel<true><<<512, 256, 0, stream>>>(x, w, nullptr, out);
    }
}